// Round 9
// baseline (1058.008 us; speedup 1.0000x reference)
//
#include <hip/hip_runtime.h>
#include <hip/hip_bf16.h>

#define N_NODES 50000
#define N_EDGES 200000
#define NTILES  (N_EDGES / 32)      // 6250 tiles of 32 edges
#define EBLK    768                 // 3 blocks/CU (LDS-limited)
#define TWAVES  (EBLK * 4)          // 3072 persistent waves

typedef float  v2f    __attribute__((ext_vector_type(2)));
typedef float  f32x16 __attribute__((ext_vector_type(16)));
typedef short  s16x8  __attribute__((ext_vector_type(8)));

static __device__ inline v2f sp2(float s) { v2f r; r.x = s; r.y = s; return r; }

static __device__ inline v2f fma2(v2f a, v2f b, v2f c) {
#if __has_builtin(__builtin_elementwise_fma)
    return __builtin_elementwise_fma(a, b, c);
#else
    v2f r; r.x = fmaf(a.x, b.x, c.x); r.y = fmaf(a.y, b.y, c.y); return r;
#endif
}

static __device__ inline v2f max2(v2f a, v2f b) {
#if __has_builtin(__builtin_elementwise_max)
    return __builtin_elementwise_max(a, b);
#else
    v2f r; r.x = fmaxf(a.x, b.x); r.y = fmaxf(a.y, b.y); return r;
#endif
}

static __device__ inline unsigned short bf_rne(float f) {
    unsigned int u = __float_as_uint(f);
    u += 0x7fffu + ((u >> 16) & 1u);
    return (unsigned short)(u >> 16);
}

// ---------------------------------------------------------------------------
// CSR build: histogram + single-block exclusive scan
// ---------------------------------------------------------------------------
__global__ void hist_kernel(const int* __restrict__ ei, int* __restrict__ cnt)
{
    const int e = blockIdx.x * 256 + threadIdx.x;
    if (e < N_EDGES) atomicAdd(&cnt[ei[N_EDGES + e]], 1);
}

__global__ __launch_bounds__(1024) void scan_kernel(
    const int* __restrict__ cnt, int* __restrict__ off, int* __restrict__ cur)
{
    __shared__ int ps[1024];
    const int t = threadIdx.x;
    const int base = t * 49;                    // 1024*49 = 50176 >= 50000
    int s = 0;
    for (int j = 0; j < 49; ++j) {
        const int idx = base + j;
        if (idx < N_NODES) s += cnt[idx];
    }
    ps[t] = s;
    __syncthreads();
    for (int d = 1; d < 1024; d <<= 1) {        // Hillis-Steele inclusive
        const int v = (t >= d) ? ps[t - d] : 0;
        __syncthreads();
        ps[t] += v;
        __syncthreads();
    }
    int run = ps[t] - s;                        // exclusive prefix
    for (int j = 0; j < 49; ++j) {
        const int idx = base + j;
        if (idx < N_NODES) {
            off[idx] = run;
            cur[idx] = run;
            run += cnt[idx];
        }
    }
    if (t == 1023) off[N_NODES] = ps[1023];     // sentinel = N_EDGES
}

// ---------------------------------------------------------------------------
// Edge kernel (MFMA), R7 structure. MODE 0: atomicAdd into agg (fallback).
// MODE 1: CSR — claim slot via int atomic on cur[dst], write full-line msg.
// ---------------------------------------------------------------------------
template <int MODE>
__global__ __launch_bounds__(256, 3) void edge_kernel_t(
    const float* __restrict__ x, const int* __restrict__ ei,
    const float* __restrict__ ea, const float* __restrict__ nn_w,
    const float* __restrict__ nn_b, float* __restrict__ dstbuf,
    int* __restrict__ cur)
{
    __shared__ unsigned short wT[1024 * 16];   // 32 KB: [col=i*32+o][16 bf16]
    __shared__ float tl4[4][32 * 33];          // 16.9 KB: per-wave msg transpose

    for (int c = threadIdx.x; c < 1024; c += 256) {
        unsigned short row[16];
#pragma unroll
        for (int k = 0; k < 8; ++k) row[k] = bf_rne(nn_w[k * 1024 + c]);
#pragma unroll
        for (int k = 0; k < 7; ++k) row[8 + k] = row[k];
        row[15] = bf_rne(nn_b[c]);
        unsigned int w[8];
#pragma unroll
        for (int q = 0; q < 8; ++q)
            w[q] = (unsigned int)row[2 * q] | ((unsigned int)row[2 * q + 1] << 16);
        uint4* p = (uint4*)(wT + c * 16);
        uint4 lo_; lo_.x = w[0]; lo_.y = w[1]; lo_.z = w[2]; lo_.w = w[3];
        uint4 hi_; hi_.x = w[4]; hi_.y = w[5]; hi_.z = w[6]; hi_.w = w[7];
        p[0] = lo_; p[1] = hi_;
    }
    __syncthreads();

    const int lane = threadIdx.x & 63;
    const int eo   = lane & 31;
    const int hsel = lane >> 5;
    float* tl = tl4[threadIdx.x >> 6];

    int t = (int)((blockIdx.x * 256u + threadIdx.x) >> 6);
    if (t >= NTILES) return;

    int    sc  = ei[t * 32 + eo];
    int    dc  = ei[N_EDGES + t * 32 + eo];
    float4 ea0 = ((const float4*)(ea + (size_t)(t * 32 + eo) * 8))[0];
    float4 ea1 = ((const float4*)(ea + (size_t)(t * 32 + eo) * 8))[1];

    float4 xq[8];
    {
        const float4* xp = (const float4*)(x + (size_t)sc * 32);
#pragma unroll
        for (int q = 0; q < 8; ++q) xq[q] = xp[q];
    }

    int tn = t + TWAVES;
    int tc = tn < NTILES ? tn : t;
    int    sn  = ei[tc * 32 + eo];
    int    dn  = ei[N_EDGES + tc * 32 + eo];
    float4 na0 = ((const float4*)(ea + (size_t)(tc * 32 + eo) * 8))[0];
    float4 na1 = ((const float4*)(ea + (size_t)(tc * 32 + eo) * 8))[1];

    const f32x16 zf = {0.f,0.f,0.f,0.f,0.f,0.f,0.f,0.f,
                       0.f,0.f,0.f,0.f,0.f,0.f,0.f,0.f};

    while (true) {
        const float ef[8] = {ea0.x, ea0.y, ea0.z, ea0.w,
                             ea1.x, ea1.y, ea1.z, ea1.w};
        s16x8 bfrag;
#pragma unroll
        for (int j = 0; j < 8; ++j) {
            const float f = ef[j];
            const unsigned short hi = bf_rne(f);
            unsigned short v;
            if (j < 7) {
                const unsigned short lo =
                    bf_rne(f - __uint_as_float(((unsigned int)hi) << 16));
                v = hsel ? lo : hi;
            } else {
                v = hsel ? (unsigned short)0x3F80 : hi;
            }
            bfrag[j] = (short)v;
        }

        const float4* xpn = (const float4*)(x + (size_t)sn * 32);

        v2f m2[8];
#pragma unroll
        for (int p = 0; p < 8; ++p) m2[p] = sp2(0.f);

#pragma unroll
        for (int i = 0; i < 32; ++i) {
            const s16x8 a = *(const s16x8*)(wT + (i * 32 + eo) * 16 + hsel * 8);
            const f32x16 d =
                __builtin_amdgcn_mfma_f32_32x32x16_bf16(a, bfrag, zf, 0, 0, 0);
            const float4 xc = xq[i >> 2];
            const float xv = (i & 3) == 0 ? xc.x : (i & 3) == 1 ? xc.y
                           : (i & 3) == 2 ? xc.z : xc.w;
            const v2f x2 = sp2(xv);
#pragma unroll
            for (int p = 0; p < 8; ++p) {
                v2f dd; dd.x = d[2 * p]; dd.y = d[2 * p + 1];
                m2[p] = fma2(x2, max2(dd, sp2(0.f)), m2[p]);
            }
            if ((i & 3) == 3) xq[i >> 2] = xpn[i >> 2];
        }

        // slot claim (CSR): one 4B int atomic per edge, lanes 0..31 only
        int slotv = 0;
        if (MODE == 1 && lane < 32) slotv = atomicAdd(&cur[dc], 1);

        // transpose msg through LDS: tl[o][e] (33-stride, conflict-free)
#pragma unroll
        for (int p = 0; p < 8; ++p) {
            const int r0 = 2 * p, r1 = 2 * p + 1;
            const int o0 = (r0 & 3) + 8 * (r0 >> 2) + 4 * hsel;
            const int o1 = (r1 & 3) + 8 * (r1 >> 2) + 4 * hsel;
            tl[o0 * 33 + eo] = m2[p].x;
            tl[o1 * 33 + eo] = m2[p].y;
        }

        // write phase: 2 edges per round, 32 contiguous lanes each
#pragma unroll
        for (int r = 0; r < 16; ++r) {
            const float v = tl[eo * 33 + 2 * r + hsel];
            if (MODE == 1) {
                const int s0 = __builtin_amdgcn_readlane(slotv, 2 * r);
                const int s1 = __builtin_amdgcn_readlane(slotv, 2 * r + 1);
                const int sr = hsel ? s1 : s0;
                dstbuf[(size_t)sr * 32 + eo] = v;
            } else {
                const int d0i = __builtin_amdgcn_readlane(dc, 2 * r);
                const int d1i = __builtin_amdgcn_readlane(dc, 2 * r + 1);
                const int dr  = hsel ? d1i : d0i;
                unsafeAtomicAdd(&dstbuf[(size_t)dr * 32 + eo], v);
            }
        }

        if (tn >= NTILES) break;
        t = tn; sc = sn; dc = dn; ea0 = na0; ea1 = na1;
        tn = t + TWAVES; tc = tn < NTILES ? tn : t;
        sn  = ei[tc * 32 + eo];
        dn  = ei[N_EDGES + tc * 32 + eo];
        na0 = ((const float4*)(ea + (size_t)(tc * 32 + eo) * 8))[0];
        na1 = ((const float4*)(ea + (size_t)(tc * 32 + eo) * 8))[1];
    }
}

// ---------------------------------------------------------------------------
// Finalize: one THREAD per node. MODE 0: read agg row. MODE 1: gather CSR
// rows [off[n], off[n+1]) from msgbuf (sequential in memory).
// Then h = agg + x@root + bias -> LN -> relu -> lin.
// ---------------------------------------------------------------------------
template <int MODE>
__global__ __launch_bounds__(256) void finalize_kernel_t(
    const float* __restrict__ msgbuf, const int* __restrict__ off,
    const float* __restrict__ x,
    const float* __restrict__ root, const float* __restrict__ bias,
    const float* __restrict__ norm_w, const float* __restrict__ norm_b,
    const float* __restrict__ lin_w, const float* __restrict__ lin_b,
    float* __restrict__ out)
{
    __shared__ v2f rlds[512];            // root  [32 i][16 oo]
    __shared__ v2f llds[256];            // lin_w [32 o][8 jj]
    __shared__ v2f blds[16], nwl[16], nbl[16], lbl[8];

    const int t = threadIdx.x;
    for (int f = t; f < 1024; f += 256) ((float*)rlds)[f] = root[f];
    for (int f = t; f < 512;  f += 256) ((float*)llds)[f] = lin_w[f];
    if (t < 32) {
        ((float*)blds)[t] = bias[t];
        ((float*)nwl)[t]  = norm_w[t];
        ((float*)nbl)[t]  = norm_b[t];
    }
    if (t < 16) ((float*)lbl)[t] = lin_b[t];
    __syncthreads();

    const int n = blockIdx.x * 256 + t;
    if (n >= N_NODES) return;

    float4 xf[8];
    {
        const float4* xp = (const float4*)(x + (size_t)n * 32);
#pragma unroll
        for (int q = 0; q < 8; ++q) xf[q] = xp[q];
    }

    v2f h[16];
#pragma unroll
    for (int oo = 0; oo < 16; ++oo) h[oo] = blds[oo];

    if (MODE == 1) {
        const int rs = off[n], re = off[n + 1];
        for (int r = rs; r < re; ++r) {
            const float4* mp = (const float4*)(msgbuf + (size_t)r * 32);
#pragma unroll
            for (int q = 0; q < 8; ++q) {
                const float4 m = mp[q];
                v2f a; a.x = m.x; a.y = m.y;
                v2f b; b.x = m.z; b.y = m.w;
                h[2 * q]     += a;
                h[2 * q + 1] += b;
            }
        }
    } else {
        const float4* ap = (const float4*)(msgbuf + (size_t)n * 32);
#pragma unroll
        for (int q = 0; q < 8; ++q) {
            const float4 m = ap[q];
            v2f a; a.x = m.x; a.y = m.y;
            v2f b; b.x = m.z; b.y = m.w;
            h[2 * q]     += a;
            h[2 * q + 1] += b;
        }
    }

#pragma unroll
    for (int i = 0; i < 32; ++i) {
        const float xi = ((const float*)xf)[i];
#pragma unroll
        for (int oo = 0; oo < 16; ++oo)
            h[oo] = fma2(sp2(xi), rlds[i * 16 + oo], h[oo]);
    }

    v2f sv = h[0];
#pragma unroll
    for (int oo = 1; oo < 16; ++oo) sv += h[oo];
    const float mu = (sv.x + sv.y) * (1.f / 32.f);
    const v2f mu2 = sp2(mu);
    v2f qv = (h[0] - mu2) * (h[0] - mu2);
#pragma unroll
    for (int oo = 1; oo < 16; ++oo) {
        const v2f dd = h[oo] - mu2;
        qv = fma2(dd, dd, qv);
    }
    const float var = (qv.x + qv.y) * (1.f / 32.f);
    const float rs2 = rsqrtf(var + 1e-5f);

    v2f r[16];
#pragma unroll
    for (int oo = 0; oo < 16; ++oo) {
        const v2f nv = fma2((h[oo] - mu2) * sp2(rs2), nwl[oo], nbl[oo]);
        r[oo] = max2(nv, sp2(0.f));
    }

    v2f a2[8];
#pragma unroll
    for (int jj = 0; jj < 8; ++jj) a2[jj] = lbl[jj];
#pragma unroll
    for (int o = 0; o < 32; ++o) {
        const float rv = (o & 1) ? r[o >> 1].y : r[o >> 1].x;
#pragma unroll
        for (int jj = 0; jj < 8; ++jj)
            a2[jj] = fma2(sp2(rv), llds[o * 8 + jj], a2[jj]);
    }

    float4* op = (float4*)(out + (size_t)n * 16);
#pragma unroll
    for (int q = 0; q < 4; ++q) {
        float4 v;
        v.x = a2[2 * q].x; v.y = a2[2 * q].y;
        v.z = a2[2 * q + 1].x; v.w = a2[2 * q + 1].y;
        op[q] = v;
    }
}

// ---------------------------------------------------------------------------
extern "C" void kernel_launch(void* const* d_in, const int* in_sizes, int n_in,
                              void* d_out, int out_size, void* d_ws, size_t ws_size,
                              hipStream_t stream)
{
    const float* x      = (const float*)d_in[0];
    const int*   ei     = (const int*)  d_in[1];
    const float* ea     = (const float*)d_in[2];
    const float* nn_w   = (const float*)d_in[3];
    const float* nn_b   = (const float*)d_in[4];
    const float* root   = (const float*)d_in[5];
    const float* bias   = (const float*)d_in[6];
    const float* norm_w = (const float*)d_in[7];
    const float* norm_b = (const float*)d_in[8];
    const float* lin_w  = (const float*)d_in[9];
    const float* lin_b  = (const float*)d_in[10];
    float* out = (float*)d_out;

    // ws layout (CSR path): msgbuf | cnt | off | cur
    const size_t need = (size_t)N_EDGES * 32 * 4 + (size_t)(50000 + 50004 + 50000) * 4;

    if (ws_size >= need) {
        float* msgbuf = (float*)d_ws;
        int*   cnt    = (int*)((char*)d_ws + (size_t)N_EDGES * 32 * 4);
        int*   off    = cnt + 50000;
        int*   cur    = off + 50004;

        hipMemsetAsync(cnt, 0, (size_t)N_NODES * 4, stream);
        hist_kernel<<<(N_EDGES + 255) / 256, 256, 0, stream>>>(ei, cnt);
        scan_kernel<<<1, 1024, 0, stream>>>(cnt, off, cur);
        edge_kernel_t<1><<<EBLK, 256, 0, stream>>>(x, ei, ea, nn_w, nn_b,
                                                   msgbuf, cur);
        finalize_kernel_t<1><<<(N_NODES + 255) / 256, 256, 0, stream>>>(
            msgbuf, off, x, root, bias, norm_w, norm_b, lin_w, lin_b, out);
    } else {
        float* agg = (float*)d_ws;   // 6.4 MB
        hipMemsetAsync(agg, 0, (size_t)N_NODES * 32 * sizeof(float), stream);
        edge_kernel_t<0><<<EBLK, 256, 0, stream>>>(x, ei, ea, nn_w, nn_b,
                                                   agg, nullptr);
        finalize_kernel_t<0><<<(N_NODES + 255) / 256, 256, 0, stream>>>(
            agg, nullptr, x, root, bias, norm_w, norm_b, lin_w, lin_b, out);
    }
}

// Round 10
// 119.456 us; speedup vs baseline: 8.8569x; 8.8569x over previous
//
#include <hip/hip_runtime.h>
#include <hip/hip_bf16.h>

#define N_NODES 50000
#define N_EDGES 200000
#define NTILES  (N_EDGES / 32)      // 6250 tiles of 32 edges
#define EBLK    768                 // 3 blocks/CU (LDS-limited)
#define TWAVES  (EBLK * 4)          // 3072 persistent waves

typedef float  v2f    __attribute__((ext_vector_type(2)));
typedef float  f32x16 __attribute__((ext_vector_type(16)));
typedef short  s16x8  __attribute__((ext_vector_type(8)));

static __device__ inline v2f sp2(float s) { v2f r; r.x = s; r.y = s; return r; }

static __device__ inline v2f fma2(v2f a, v2f b, v2f c) {
#if __has_builtin(__builtin_elementwise_fma)
    return __builtin_elementwise_fma(a, b, c);
#else
    v2f r; r.x = fmaf(a.x, b.x, c.x); r.y = fmaf(a.y, b.y, c.y); return r;
#endif
}

static __device__ inline v2f max2(v2f a, v2f b) {
#if __has_builtin(__builtin_elementwise_max)
    return __builtin_elementwise_max(a, b);
#else
    v2f r; r.x = fmaxf(a.x, b.x); r.y = fmaxf(a.y, b.y); return r;
#endif
}

static __device__ inline unsigned short bf_rne(float f) {
    unsigned int u = __float_as_uint(f);
    u += 0x7fffu + ((u >> 16) & 1u);
    return (unsigned short)(u >> 16);
}

// ---------------------------------------------------------------------------
// Edge kernel (MFMA, R7 structure). Per 32-edge tile, per i (0..31):
//   D[o][e] = mfma_32x32x16_bf16(A, B);  msg[e][o] += x[src[e]][i]*relu(D[o][e])
// Scatter: global_atomic_pk_add_bf16 — 16 atomic ops/edge (was 32 fp32),
// agg is bf16[32] per node. 8 rounds x 4 edges x 16 lanes, 64 B/edge.
// ---------------------------------------------------------------------------
__global__ __launch_bounds__(256, 3) void edge_kernel(
    const float* __restrict__ x, const int* __restrict__ ei,
    const float* __restrict__ ea, const float* __restrict__ nn_w,
    const float* __restrict__ nn_b, unsigned short* __restrict__ aggb)
{
    __shared__ unsigned short wT[1024 * 16];   // 32 KB: [col=i*32+o][16 bf16]
    __shared__ float tl4[4][32 * 33];          // 16.9 KB: per-wave msg transpose

    // ---- prologue: weights -> bf16, K-layout [w0..w7 | w0..w6, bias] ----
    for (int c = threadIdx.x; c < 1024; c += 256) {
        unsigned short row[16];
#pragma unroll
        for (int k = 0; k < 8; ++k) row[k] = bf_rne(nn_w[k * 1024 + c]);
#pragma unroll
        for (int k = 0; k < 7; ++k) row[8 + k] = row[k];
        row[15] = bf_rne(nn_b[c]);
        unsigned int w[8];
#pragma unroll
        for (int q = 0; q < 8; ++q)
            w[q] = (unsigned int)row[2 * q] | ((unsigned int)row[2 * q + 1] << 16);
        uint4* p = (uint4*)(wT + c * 16);
        uint4 lo_; lo_.x = w[0]; lo_.y = w[1]; lo_.z = w[2]; lo_.w = w[3];
        uint4 hi_; hi_.x = w[4]; hi_.y = w[5]; hi_.z = w[6]; hi_.w = w[7];
        p[0] = lo_; p[1] = hi_;
    }
    __syncthreads();

    const int lane = threadIdx.x & 63;
    const int eo   = lane & 31;          // edge slot (compute phase)
    const int hsel = lane >> 5;
    float* tl = tl4[threadIdx.x >> 6];

    int t = (int)((blockIdx.x * 256u + threadIdx.x) >> 6);   // wave id = first tile
    if (t >= NTILES) return;

    // meta for tile t
    int    sc  = ei[t * 32 + eo];
    int    dc  = ei[N_EDGES + t * 32 + eo];
    float4 ea0 = ((const float4*)(ea + (size_t)(t * 32 + eo) * 8))[0];
    float4 ea1 = ((const float4*)(ea + (size_t)(t * 32 + eo) * 8))[1];

    // x rows for tile t (per-lane gather, 32 floats)
    float4 xq[8];
    {
        const float4* xp = (const float4*)(x + (size_t)sc * 32);
#pragma unroll
        for (int q = 0; q < 8; ++q) xq[q] = xp[q];
    }

    // meta for tile t+TWAVES (clamped)
    int tn = t + TWAVES;
    int tc = tn < NTILES ? tn : t;
    int    sn  = ei[tc * 32 + eo];
    int    dn  = ei[N_EDGES + tc * 32 + eo];
    float4 na0 = ((const float4*)(ea + (size_t)(tc * 32 + eo) * 8))[0];
    float4 na1 = ((const float4*)(ea + (size_t)(tc * 32 + eo) * 8))[1];

    const f32x16 zf = {0.f,0.f,0.f,0.f,0.f,0.f,0.f,0.f,
                       0.f,0.f,0.f,0.f,0.f,0.f,0.f,0.f};

    while (true) {
        // ---- B fragment: [ea_hi(8) | ea_lo(7), 1.0] ----
        const float ef[8] = {ea0.x, ea0.y, ea0.z, ea0.w,
                             ea1.x, ea1.y, ea1.z, ea1.w};
        s16x8 bfrag;
#pragma unroll
        for (int j = 0; j < 8; ++j) {
            const float f = ef[j];
            const unsigned short hi = bf_rne(f);
            unsigned short v;
            if (j < 7) {
                const unsigned short lo =
                    bf_rne(f - __uint_as_float(((unsigned int)hi) << 16));
                v = hsel ? lo : hi;
            } else {
                v = hsel ? (unsigned short)0x3F80 : hi;
            }
            bfrag[j] = (short)v;
        }

        const float4* xpn = (const float4*)(x + (size_t)sn * 32);

        v2f m2[8];
#pragma unroll
        for (int p = 0; p < 8; ++p) m2[p] = sp2(0.f);

        // ---- main loop: 32 MFMAs + packed relu/msg; x(t+1) prefetch fused ----
#pragma unroll
        for (int i = 0; i < 32; ++i) {
            const s16x8 a = *(const s16x8*)(wT + (i * 32 + eo) * 16 + hsel * 8);
            const f32x16 d =
                __builtin_amdgcn_mfma_f32_32x32x16_bf16(a, bfrag, zf, 0, 0, 0);
            const float4 xc = xq[i >> 2];
            const float xv = (i & 3) == 0 ? xc.x : (i & 3) == 1 ? xc.y
                           : (i & 3) == 2 ? xc.z : xc.w;
            const v2f x2 = sp2(xv);
#pragma unroll
            for (int p = 0; p < 8; ++p) {
                v2f dd; dd.x = d[2 * p]; dd.y = d[2 * p + 1];
                m2[p] = fma2(x2, max2(dd, sp2(0.f)), m2[p]);
            }
            if ((i & 3) == 3) xq[i >> 2] = xpn[i >> 2];   // prefetch next tile
        }

        // ---- transpose msg through LDS: tl[o][e] (33-stride, conflict-free) --
#pragma unroll
        for (int p = 0; p < 8; ++p) {
            const int r0 = 2 * p, r1 = 2 * p + 1;
            const int o0 = (r0 & 3) + 8 * (r0 >> 2) + 4 * hsel;
            const int o1 = (r1 & 3) + 8 * (r1 >> 2) + 4 * hsel;
            tl[o0 * 33 + eo] = m2[p].x;
            tl[o1 * 33 + eo] = m2[p].y;
        }

        // ---- pk_add_bf16 atomics: 8 rounds x 4 edges, 16 lanes/edge (64 B) --
        const int g = lane >> 4;        // edge sub-slot 0..3
        const int L = lane & 15;        // feature pair {2L, 2L+1}
#pragma unroll
        for (int r = 0; r < 8; ++r) {
            const int eidx = 4 * r + g;
            const int dr = __shfl(dc, eidx, 64);          // dst of edge eidx
            const float f0 = tl[(2 * L) * 33 + eidx];
            const float f1 = tl[(2 * L + 1) * 33 + eidx];
            const unsigned int pk =
                (unsigned int)bf_rne(f0) | ((unsigned int)bf_rne(f1) << 16);
            unsigned short* ap = aggb + (size_t)dr * 32 + 2 * L;
            asm volatile("global_atomic_pk_add_bf16 %0, %1, off"
                         :: "v"(ap), "v"(pk) : "memory");
        }

        if (tn >= NTILES) break;
        t = tn; sc = sn; dc = dn; ea0 = na0; ea1 = na1;
        tn = t + TWAVES; tc = tn < NTILES ? tn : t;
        sn  = ei[tc * 32 + eo];
        dn  = ei[N_EDGES + tc * 32 + eo];
        na0 = ((const float4*)(ea + (size_t)(tc * 32 + eo) * 8))[0];
        na1 = ((const float4*)(ea + (size_t)(tc * 32 + eo) * 8))[1];
    }
}

// ---------------------------------------------------------------------------
// Finalize: one THREAD per node. h = agg(bf16) + x@root + bias -> LN -> relu
// -> lin. All weights LDS-broadcast; no cross-lane ops.
// ---------------------------------------------------------------------------
__global__ __launch_bounds__(256) void finalize_kernel(
    const unsigned short* __restrict__ aggb, const float* __restrict__ x,
    const float* __restrict__ root, const float* __restrict__ bias,
    const float* __restrict__ norm_w, const float* __restrict__ norm_b,
    const float* __restrict__ lin_w, const float* __restrict__ lin_b,
    float* __restrict__ out)
{
    __shared__ v2f rlds[512];            // root  [32 i][16 oo]
    __shared__ v2f llds[256];            // lin_w [32 o][8 jj]
    __shared__ v2f blds[16], nwl[16], nbl[16], lbl[8];

    const int t = threadIdx.x;
    for (int f = t; f < 1024; f += 256) ((float*)rlds)[f] = root[f];
    for (int f = t; f < 512;  f += 256) ((float*)llds)[f] = lin_w[f];
    if (t < 32) {
        ((float*)blds)[t] = bias[t];
        ((float*)nwl)[t]  = norm_w[t];
        ((float*)nbl)[t]  = norm_b[t];
    }
    if (t < 16) ((float*)lbl)[t] = lin_b[t];
    __syncthreads();

    const int n = blockIdx.x * 256 + t;
    if (n >= N_NODES) return;

    float4 xf[8];
    {
        const float4* xp = (const float4*)(x + (size_t)n * 32);
#pragma unroll
        for (int q = 0; q < 8; ++q) xf[q] = xp[q];
    }

    // agg row: 32 bf16 = 64 B = 4x uint4; dword w -> features (lo, hi)
    uint4 ws[4];
    {
        const uint4* ap = (const uint4*)(aggb + (size_t)n * 32);
#pragma unroll
        for (int q = 0; q < 4; ++q) ws[q] = ap[q];
    }

    v2f h[16];
#pragma unroll
    for (int q = 0; q < 4; ++q) {
        const unsigned int wq[4] = {ws[q].x, ws[q].y, ws[q].z, ws[q].w};
#pragma unroll
        for (int c = 0; c < 4; ++c) {
            const int oo = q * 4 + c;
            v2f a;
            a.x = __uint_as_float(wq[c] << 16);
            a.y = __uint_as_float(wq[c] & 0xFFFF0000u);
            h[oo] = a + blds[oo];
        }
    }

#pragma unroll
    for (int i = 0; i < 32; ++i) {
        const float xi = ((const float*)xf)[i];
#pragma unroll
        for (int oo = 0; oo < 16; ++oo)
            h[oo] = fma2(sp2(xi), rlds[i * 16 + oo], h[oo]);
    }

    v2f sv = h[0];
#pragma unroll
    for (int oo = 1; oo < 16; ++oo) sv += h[oo];
    const float mu = (sv.x + sv.y) * (1.f / 32.f);
    const v2f mu2 = sp2(mu);
    v2f qv = (h[0] - mu2) * (h[0] - mu2);
#pragma unroll
    for (int oo = 1; oo < 16; ++oo) {
        const v2f dd = h[oo] - mu2;
        qv = fma2(dd, dd, qv);
    }
    const float var = (qv.x + qv.y) * (1.f / 32.f);
    const float rs = rsqrtf(var + 1e-5f);

    v2f r[16];
#pragma unroll
    for (int oo = 0; oo < 16; ++oo) {
        const v2f nv = fma2((h[oo] - mu2) * sp2(rs), nwl[oo], nbl[oo]);
        r[oo] = max2(nv, sp2(0.f));
    }

    v2f a2[8];
#pragma unroll
    for (int jj = 0; jj < 8; ++jj) a2[jj] = lbl[jj];
#pragma unroll
    for (int o = 0; o < 32; ++o) {
        const float rv = (o & 1) ? r[o >> 1].y : r[o >> 1].x;
#pragma unroll
        for (int jj = 0; jj < 8; ++jj)
            a2[jj] = fma2(sp2(rv), llds[o * 8 + jj], a2[jj]);
    }

    float4* op = (float4*)(out + (size_t)n * 16);
#pragma unroll
    for (int q = 0; q < 4; ++q) {
        float4 v;
        v.x = a2[2 * q].x; v.y = a2[2 * q].y;
        v.z = a2[2 * q + 1].x; v.w = a2[2 * q + 1].y;
        op[q] = v;
    }
}

// ---------------------------------------------------------------------------
extern "C" void kernel_launch(void* const* d_in, const int* in_sizes, int n_in,
                              void* d_out, int out_size, void* d_ws, size_t ws_size,
                              hipStream_t stream)
{
    const float* x      = (const float*)d_in[0];
    const int*   ei     = (const int*)  d_in[1];
    const float* ea     = (const float*)d_in[2];
    const float* nn_w   = (const float*)d_in[3];
    const float* nn_b   = (const float*)d_in[4];
    const float* root   = (const float*)d_in[5];
    const float* bias   = (const float*)d_in[6];
    const float* norm_w = (const float*)d_in[7];
    const float* norm_b = (const float*)d_in[8];
    const float* lin_w  = (const float*)d_in[9];
    const float* lin_b  = (const float*)d_in[10];
    float* out = (float*)d_out;

    unsigned short* aggb = (unsigned short*)d_ws;   // N_NODES * 32 bf16 = 3.2 MB

    hipMemsetAsync(aggb, 0, (size_t)N_NODES * 32 * sizeof(unsigned short), stream);
    edge_kernel<<<EBLK, 256, 0, stream>>>(x, ei, ea, nn_w, nn_b, aggb);
    finalize_kernel<<<(N_NODES + 255) / 256, 256, 0, stream>>>(
        aggb, x, root, bias, norm_w, norm_b, lin_w, lin_b, out);
}